// Round 5
// baseline (675.194 us; speedup 1.0000x reference)
//
#include <hip/hip_runtime.h>
#include <cstdint>
#include <cstddef>

// Problem constants (B=8, T=8192, D=256, H=16, K=3, decay=0.9, eps=1e-5)
// I/O dtype: float32. Internal staging: bf16 (MFMA). Residual stream: fp32
// in d_out (fast path).
#define TT 8192
#define BB 8
#define DD 256
#define NTOK (BB * TT)

typedef unsigned short u16;
typedef unsigned int u32;

typedef __attribute__((ext_vector_type(8))) short bf16x8;
typedef __attribute__((ext_vector_type(4))) float f32x4;

__device__ __forceinline__ float bf2f(u16 u) {
    u32 v = ((u32)u) << 16;
    float f;
    __builtin_memcpy(&f, &v, 4);
    return f;
}

__device__ __forceinline__ u16 f2bf(float f) {
    u32 v;
    __builtin_memcpy(&v, &f, 4);
    u32 r = (v + 0x7FFFu + ((v >> 16) & 1u)) >> 16;  // RNE
    return (u16)r;
}

__device__ __forceinline__ uint2 pack4(const float* v) {
    uint2 p;
    p.x = (u32)f2bf(v[0]) | ((u32)f2bf(v[1]) << 16);
    p.y = (u32)f2bf(v[2]) | ((u32)f2bf(v[3]) << 16);
    return p;
}

__device__ __forceinline__ void unpack4(uint2 p, float* v) {
    v[0] = bf2f((u16)(p.x & 0xFFFFu));
    v[1] = bf2f((u16)(p.x >> 16));
    v[2] = bf2f((u16)(p.y & 0xFFFFu));
    v[3] = bf2f((u16)(p.y >> 16));
}

__device__ __forceinline__ uint4 pack8(const float* v) {
    uint4 p;
    p.x = (u32)f2bf(v[0]) | ((u32)f2bf(v[1]) << 16);
    p.y = (u32)f2bf(v[2]) | ((u32)f2bf(v[3]) << 16);
    p.z = (u32)f2bf(v[4]) | ((u32)f2bf(v[5]) << 16);
    p.w = (u32)f2bf(v[6]) | ((u32)f2bf(v[7]) << 16);
    return p;
}

__device__ __forceinline__ void unpack8(uint4 p, float* v) {
    v[0] = bf2f((u16)(p.x & 0xFFFFu));
    v[1] = bf2f((u16)(p.x >> 16));
    v[2] = bf2f((u16)(p.y & 0xFFFFu));
    v[3] = bf2f((u16)(p.y >> 16));
    v[4] = bf2f((u16)(p.z & 0xFFFFu));
    v[5] = bf2f((u16)(p.z >> 16));
    v[6] = bf2f((u16)(p.w & 0xFFFFu));
    v[7] = bf2f((u16)(p.w >> 16));
}

// ---------------------------------------------------------------------------
// DIAG: ws too small -> write 512 + ws_MiB so absmax decodes ws_size.
// ---------------------------------------------------------------------------
__global__ __launch_bounds__(256) void k_diag(float* out, float code) {
    out[(size_t)blockIdx.x * 256 + threadIdx.x] = code;
}

// ---------------------------------------------------------------------------
// Weight transpose/convert fp32 -> bf16 (prep; proven in round 4).
// ---------------------------------------------------------------------------
__global__ __launch_bounds__(256) void k_transpose(
    const float* s0, const float* s1, const float* s2, const float* s3,
    const float* s4, const float* s5,
    u16* d0, u16* d1, u16* d2, u16* d3, u16* d4, u16* d5) {
    const int z = blockIdx.z;
    const float* src;
    u16* dst;
    int K, N, tr;
    switch (z) {
        case 0: src = s0; dst = d0; K = 256; N = 256; tr = 1; break;
        case 1: src = s1; dst = d1; K = 256; N = 256; tr = 1; break;
        case 2: src = s2; dst = d2; K = 256; N = 512; tr = 1; break;
        case 3: src = s3; dst = d3; K = 512; N = 256; tr = 1; break;
        case 4: src = s4; dst = d4; K = 256; N = 256; tr = 0; break;
        default: src = s5; dst = d5; K = 256; N = 256; tr = 0; break;
    }
    const int nb = blockIdx.x * 32, kb = blockIdx.y * 32;
    if (nb >= N || kb >= K) return;
    const int tx = threadIdx.x & 31, ty = threadIdx.x >> 5;
    if (!tr) {
        for (int i = ty; i < 32; i += 8)
            dst[(size_t)(kb + i) * N + nb + tx] =
                f2bf(src[(size_t)(kb + i) * N + nb + tx]);
        return;
    }
    __shared__ u16 tile[32][33];
    for (int i = ty; i < 32; i += 8)
        tile[i][tx] = f2bf(src[(size_t)(kb + i) * N + nb + tx]);
    __syncthreads();
    for (int i = ty; i < 32; i += 8)
        dst[(size_t)(nb + i) * K + kb + tx] = tile[tx][i];
}

// ---------------------------------------------------------------------------
// Composed bias (fp32): bc[n] = sum_j bv[j]*Wo[j][n] + bo[n].
// ---------------------------------------------------------------------------
__global__ __launch_bounds__(256) void k_bias_compose(
    const float* tbv, const float* tWo, const float* tbo,
    const float* abv, const float* aWo, const float* abo,
    float* bc1, float* bc2) {
    const float* bv = blockIdx.x ? abv : tbv;
    const float* Wo = blockIdx.x ? aWo : tWo;
    const float* bo = blockIdx.x ? abo : tbo;
    float* bc = blockIdx.x ? bc2 : bc1;
    const int n = threadIdx.x;
    float s = bo[n];
    for (int j = 0; j < 256; j++) s += bv[j] * Wo[j * 256 + n];
    bc[n] = s;
}

// ---------------------------------------------------------------------------
// LN1 + temporal decay window (H=16, left zero-pad per batch). fp32 in,
// bf16 out.
// ---------------------------------------------------------------------------
__global__ __launch_bounds__(256) void k_ln_temporal(
    const float* __restrict__ x, const float* __restrict__ gw,
    const float* __restrict__ bw, u16* __restrict__ out) {
    const int b = blockIdx.y;
    const int t0 = blockIdx.x * 64;
    const int tid = threadIdx.x;
    const int wv = tid >> 6, lane = tid & 63;
    const int d4 = lane * 4;
    __shared__ u16 hl[79 * 256];

    const float4 gv = *(const float4*)(gw + d4);
    const float4 bv = *(const float4*)(bw + d4);

    for (int i = wv; i < 79; i += 4) {
        const int t = t0 + i - 15;
        if (t < 0) {
            *(uint2*)(hl + i * 256 + d4) = make_uint2(0u, 0u);
            continue;
        }
        const float4 v = *(const float4*)(x + ((size_t)b * TT + t) * DD + d4);
        float s = v.x + v.y + v.z + v.w;
        float ss = v.x * v.x + v.y * v.y + v.z * v.z + v.w * v.w;
        for (int m = 1; m < 64; m <<= 1) {
            s += __shfl_xor(s, m);
            ss += __shfl_xor(ss, m);
        }
        const float mean = s * (1.0f / 256.0f);
        const float var = ss * (1.0f / 256.0f) - mean * mean;
        const float rs = rsqrtf(fmaxf(var, 0.f) + 1e-5f);
        float h[4] = {(v.x - mean) * rs * gv.x + bv.x,
                      (v.y - mean) * rs * gv.y + bv.y,
                      (v.z - mean) * rs * gv.z + bv.z,
                      (v.w - mean) * rs * gv.w + bv.w};
        *(uint2*)(hl + i * 256 + d4) = pack4(h);
    }
    __syncthreads();

    float tw[16];
    {
        float p = 1.f, s = 0.f;
        for (int j = 0; j < 16; j++) {
            tw[j] = p;
            s += p;
            p *= 0.9f;
        }
        const float inv = 1.f / s;
        for (int j = 0; j < 16; j++) tw[j] *= inv;
    }
    const int dc = (tid & 63) * 4;
    const int tg = (tid >> 6) * 16;
    for (int ot = tg; ot < tg + 16; ++ot) {
        float a[4] = {0.f, 0.f, 0.f, 0.f};
        for (int j = 0; j < 16; j++) {
            float h[4];
            unpack4(*(const uint2*)(hl + (ot + j) * 256 + dc), h);
            a[0] += tw[j] * h[0];
            a[1] += tw[j] * h[1];
            a[2] += tw[j] * h[2];
            a[3] += tw[j] * h[3];
        }
        *(uint2*)(out + ((size_t)b * TT + t0 + ot) * DD + dc) = pack4(a);
    }
}

// ---------------------------------------------------------------------------
// LN2 + neighbor window (fallback path only).
// ---------------------------------------------------------------------------
__global__ __launch_bounds__(256) void k_ln_neighbor(
    const float* __restrict__ x, const float* __restrict__ gw,
    const float* __restrict__ bw, u16* __restrict__ out) {
    const int b = blockIdx.y;
    const int t0 = blockIdx.x * 64;
    const int tid = threadIdx.x;
    const int wv = tid >> 6, lane = tid & 63;
    const int d4 = lane * 4;
    __shared__ u16 hl[66 * 256];

    const float4 gv = *(const float4*)(gw + d4);
    const float4 bv = *(const float4*)(bw + d4);

    for (int i = wv; i < 66; i += 4) {
        int t = t0 + i - 1;
        t = t < 0 ? 0 : (t >= TT ? TT - 1 : t);
        const float4 v = *(const float4*)(x + ((size_t)b * TT + t) * DD + d4);
        float s = v.x + v.y + v.z + v.w;
        float ss = v.x * v.x + v.y * v.y + v.z * v.z + v.w * v.w;
        for (int m = 1; m < 64; m <<= 1) {
            s += __shfl_xor(s, m);
            ss += __shfl_xor(ss, m);
        }
        const float mean = s * (1.0f / 256.0f);
        const float var = ss * (1.0f / 256.0f) - mean * mean;
        const float rs = rsqrtf(fmaxf(var, 0.f) + 1e-5f);
        float h[4] = {(v.x - mean) * rs * gv.x + bv.x,
                      (v.y - mean) * rs * gv.y + bv.y,
                      (v.z - mean) * rs * gv.z + bv.z,
                      (v.w - mean) * rs * gv.w + bv.w};
        *(uint2*)(hl + i * 256 + d4) = pack4(h);
    }
    __syncthreads();

    const int dc = (tid & 63) * 4;
    const int tg = (tid >> 6) * 16;
    const float third = 1.0f / 3.0f;
    for (int ot = tg; ot < tg + 16; ++ot) {
        float a[4] = {0.f, 0.f, 0.f, 0.f};
        for (int j = 0; j < 3; j++) {
            float h[4];
            unpack4(*(const uint2*)(hl + (ot + j) * 256 + dc), h);
            a[0] += h[0];
            a[1] += h[1];
            a[2] += h[2];
            a[3] += h[3];
        }
        a[0] *= third;
        a[1] *= third;
        a[2] *= third;
        a[3] *= third;
        *(uint2*)(out + ((size_t)b * TT + t0 + ot) * DD + dc) = pack4(a);
    }
}

// ---------------------------------------------------------------------------
// Plain LayerNorm (fallback path only).
// ---------------------------------------------------------------------------
__global__ __launch_bounds__(256) void k_ln(
    const float* __restrict__ x, const float* __restrict__ gw,
    const float* __restrict__ bw, u16* __restrict__ out) {
    const int tok = blockIdx.x * 4 + (threadIdx.x >> 6);
    const int lane = threadIdx.x & 63;
    const int d4 = lane * 4;
    const float4 gv = *(const float4*)(gw + d4);
    const float4 bv = *(const float4*)(bw + d4);
    const float4 v = *(const float4*)(x + (size_t)tok * DD + d4);
    float s = v.x + v.y + v.z + v.w;
    float ss = v.x * v.x + v.y * v.y + v.z * v.z + v.w * v.w;
    for (int m = 1; m < 64; m <<= 1) {
        s += __shfl_xor(s, m);
        ss += __shfl_xor(ss, m);
    }
    const float mean = s * (1.0f / 256.0f);
    const float var = ss * (1.0f / 256.0f) - mean * mean;
    const float rs = rsqrtf(fmaxf(var, 0.f) + 1e-5f);
    float h[4] = {(v.x - mean) * rs * gv.x + bv.x,
                  (v.y - mean) * rs * gv.y + bv.y,
                  (v.z - mean) * rs * gv.z + bv.z,
                  (v.w - mean) * rs * gv.w + bv.w};
    *(uint2*)(out + (size_t)tok * DD + d4) = pack4(h);
}

// ---------------------------------------------------------------------------
// Old-style MFMA GEMM (fallback path + tiny weight-compose GEMMs).
// ---------------------------------------------------------------------------
template <int EPI, typename OT>
__global__ __launch_bounds__(256) void k_gemm(
    const u16* __restrict__ A, const u16* __restrict__ Wt,
    const float* __restrict__ bias, const float* res,
    OT* out, int M, int K, int Nc, int ldw) {
    const int m0 = blockIdx.y * 128;
    const int n0 = blockIdx.x * 128;
    const int tid = threadIdx.x;
    const int wv = tid >> 6, lane = tid & 63;
    const int quad = lane >> 4, l16 = lane & 15;
    const int wm = (wv >> 1) * 64, wn = (wv & 1) * 64;

    __shared__ u16 lA[128 * 40];
    __shared__ u16 lB[128 * 40];

    f32x4 acc[4][4];
#pragma unroll
    for (int i = 0; i < 4; i++)
#pragma unroll
        for (int j = 0; j < 4; j++) acc[i][j] = (f32x4){0.f, 0.f, 0.f, 0.f};

    const int r = tid >> 2;
    const int c = tid & 3;
    const int br0 = min(n0 + r, Nc - 1);
    const int br1 = min(n0 + r + 64, Nc - 1);

    for (int k0 = 0; k0 < K; k0 += 32) {
        __syncthreads();
        {
            const uint4 a0 = *(const uint4*)(A + (size_t)(m0 + r) * K + k0 + c * 8);
            const uint4 a1 = *(const uint4*)(A + (size_t)(m0 + r + 64) * K + k0 + c * 8);
            const uint4 b0 = *(const uint4*)(Wt + (size_t)br0 * ldw + k0 + c * 8);
            const uint4 b1 = *(const uint4*)(Wt + (size_t)br1 * ldw + k0 + c * 8);
            *(uint4*)(lA + r * 40 + c * 8) = a0;
            *(uint4*)(lA + (r + 64) * 40 + c * 8) = a1;
            *(uint4*)(lB + r * 40 + c * 8) = b0;
            *(uint4*)(lB + (r + 64) * 40 + c * 8) = b1;
        }
        __syncthreads();
        bf16x8 af[4], bfr[4];
#pragma unroll
        for (int i = 0; i < 4; i++)
            af[i] = *(const bf16x8*)(lA + (wm + i * 16 + l16) * 40 + quad * 8);
#pragma unroll
        for (int j = 0; j < 4; j++)
            bfr[j] = *(const bf16x8*)(lB + (wn + j * 16 + l16) * 40 + quad * 8);
#pragma unroll
        for (int i = 0; i < 4; i++)
#pragma unroll
            for (int j = 0; j < 4; j++)
                acc[i][j] = __builtin_amdgcn_mfma_f32_16x16x32_bf16(
                    af[i], bfr[j], acc[i][j], 0, 0, 0);
    }

    float bvl[4];
    if (EPI == 1 || EPI == 2) {
#pragma unroll
        for (int j = 0; j < 4; j++)
            bvl[j] = bias[min(n0 + wn + j * 16 + l16, Nc - 1)];
    }

#pragma unroll
    for (int i = 0; i < 4; i++) {
        const int rowb = m0 + wm + i * 16 + quad * 4;
#pragma unroll
        for (int j = 0; j < 4; j++) {
            const int col = n0 + wn + j * 16 + l16;
            if (col >= Nc) continue;
#pragma unroll
            for (int rr = 0; rr < 4; rr++) {
                float v = acc[i][j][rr];
                const size_t idx = (size_t)(rowb + rr) * Nc + col;
                if (EPI == 1) {
                    v += bvl[j];
                    v = 0.5f * v * (1.0f + erff(v * 0.70710678118654752f));
                } else if (EPI == 2) {
                    v += bvl[j] + res[idx];
                } else if (EPI == 4) {
                    v += res[idx];
                }
                if constexpr (sizeof(OT) == 2)
                    out[idx] = (OT)f2bf(v);
                else
                    out[idx] = (OT)v;
            }
        }
    }
}

// ---------------------------------------------------------------------------
// Fused GEMM (fast path). Tile 128x256 (full row), 512 threads = 8 waves,
// each wave a 64x64 sub-tile (4x4 of mfma 16x16x32 bf16).
//   AMODE: 0 plain A; 1 apply 3-tap neighbor mean (edge-replicate per batch)
//          to the A rows during staging (halo rows +-1).
//   RES:   0 none; 1 fp32 residual added (coalesced via LDS).
//   OUT:   1 bf16 store (with exact GELU); 2 fp32 store.
//   LN:    1 also emit hout = LayerNorm(v)*g+b as bf16 (full row in block).
// Stores/loads all coalesced through LDS chunking (32 rows/chunk).
// res and outf may alias elementwise (in-place). K = 256 or 512; for K=512
// the second half of A columns comes from A2 (both [M][256]).
// ---------------------------------------------------------------------------
template <int AMODE, int RES, int OUT, int LN>
__global__ __launch_bounds__(512) void k_fused(
    const u16* __restrict__ A, const u16* __restrict__ A2, int K,
    const u16* __restrict__ Wt, int ldw, const float* __restrict__ bias,
    const float* res, float* outf, u16* outh,
    const float* __restrict__ lng, const float* __restrict__ lnb,
    u16* __restrict__ hout) {
    const int m0 = blockIdx.x * 128;
    const int t = threadIdx.x;
    const int lane = t & 63, wv = t >> 6;
    const int quad = lane >> 4, l16 = lane & 15;
    const int wm = (wv >> 2) * 64, wn = (wv & 3) * 64;

    __shared__ u16 sA[130 * 36];
    __shared__ u16 sA2[AMODE == 1 ? 128 * 36 : 8];
    __shared__ u16 sB[256 * 36];
    __shared__ float sRes[32 * 268];
    __shared__ float sMean[32], sRstd[32];
    __shared__ float sG[LN ? 256 : 1], sBl[LN ? 256 : 1];

    if (LN && t < 256) {
        sG[t] = lng[t];
        sBl[t] = lnb[t];
    }

    f32x4 acc[4][4];
#pragma unroll
    for (int i = 0; i < 4; i++)
#pragma unroll
        for (int j = 0; j < 4; j++) acc[i][j] = (f32x4){0.f, 0.f, 0.f, 0.f};

    int rowLo = 0, rowHi = 0;
    if (AMODE == 1) {
        rowLo = (m0 % TT == 0) ? m0 : m0 - 1;
        rowHi = ((m0 + 128) % TT == 0) ? (m0 + 127) : (m0 + 128);
    }

    const int ar = t >> 2, ac8 = (t & 3) * 8;  // A chunk: 1 per thread
    for (int k0 = 0; k0 < K; k0 += 32) {
        const u16* Asrc = (k0 >= 256) ? A2 : A;
        const int kk = k0 & 255;
        __syncthreads();
        // --- stage A ---
        if (AMODE == 0) {
            *(uint4*)(sA + ar * 36 + ac8) =
                *(const uint4*)(Asrc + (size_t)(m0 + ar) * 256 + kk + ac8);
        } else {
            *(uint4*)(sA + (ar + 1) * 36 + ac8) =
                *(const uint4*)(Asrc + (size_t)(m0 + ar) * 256 + kk + ac8);
            if (t < 8) {
                const int hr = (t >> 2) ? rowHi : rowLo;
                const int dr = (t >> 2) ? 129 : 0;
                *(uint4*)(sA + dr * 36 + (t & 3) * 8) =
                    *(const uint4*)(Asrc + (size_t)hr * 256 + kk + (t & 3) * 8);
            }
        }
        // --- stage B: 256 rows x 32 cols = 1024 chunks, 2 per thread ---
        {
            int ch = t;
            *(uint4*)(sB + (ch >> 2) * 36 + (ch & 3) * 8) =
                *(const uint4*)(Wt + (size_t)(ch >> 2) * ldw + k0 + (ch & 3) * 8);
            ch += 512;
            *(uint4*)(sB + (ch >> 2) * 36 + (ch & 3) * 8) =
                *(const uint4*)(Wt + (size_t)(ch >> 2) * ldw + k0 + (ch & 3) * 8);
        }
        __syncthreads();
        if (AMODE == 1) {
            // 3-tap mean: sA2[r] = (sA[r] + sA[r+1] + sA[r+2]) / 3
            float v0[8], v1[8], v2[8], o[8];
            unpack8(*(const uint4*)(sA + ar * 36 + ac8), v0);
            unpack8(*(const uint4*)(sA + (ar + 1) * 36 + ac8), v1);
            unpack8(*(const uint4*)(sA + (ar + 2) * 36 + ac8), v2);
#pragma unroll
            for (int e = 0; e < 8; e++)
                o[e] = (v0[e] + v1[e] + v2[e]) * (1.0f / 3.0f);
            *(uint4*)(sA2 + ar * 36 + ac8) = pack8(o);
            __syncthreads();
        }
        const u16* Af = (AMODE == 1) ? sA2 : sA;
        bf16x8 af[4], bfr[4];
#pragma unroll
        for (int i = 0; i < 4; i++)
            af[i] = *(const bf16x8*)(Af + (wm + i * 16 + l16) * 36 + quad * 8);
#pragma unroll
        for (int j = 0; j < 4; j++)
            bfr[j] = *(const bf16x8*)(sB + (wn + j * 16 + l16) * 36 + quad * 8);
#pragma unroll
        for (int i = 0; i < 4; i++)
#pragma unroll
            for (int j = 0; j < 4; j++)
                acc[i][j] = __builtin_amdgcn_mfma_f32_16x16x32_bf16(
                    af[i], bfr[j], acc[i][j], 0, 0, 0);
    }

    float bvl[4];
#pragma unroll
    for (int j = 0; j < 4; j++) bvl[j] = bias[wn + j * 16 + l16];

    // --- epilogue: 4 chunks of 32 rows, all global I/O coalesced ---
    const int rowl = t >> 4;             // 0..31
    const int colb = (t & 15) * 16;      // 0..240
    for (int cch = 0; cch < 4; cch++) {
        const int gr = m0 + cch * 32 + rowl;  // this thread's global row
        __syncthreads();  // sRes reuse guard
        if (RES) {
            const float* rp = res + (size_t)gr * 256 + colb;
            float* sp = sRes + rowl * 268 + colb;
#pragma unroll
            for (int q = 0; q < 4; q++)
                *(float4*)(sp + q * 4) = *(const float4*)(rp + q * 4);
            __syncthreads();
        }
        // add acc (+bias, +gelu) by owning waves
        if (wm == (cch >> 1) * 64) {
            const int ibase = (cch & 1) * 2;
#pragma unroll
            for (int ii = 0; ii < 2; ii++) {
                const int i = ibase + ii;
#pragma unroll
                for (int j = 0; j < 4; j++) {
#pragma unroll
                    for (int rr = 0; rr < 4; rr++) {
                        const int rl = i * 16 + quad * 4 + rr - (cch & 1) * 32;
                        const int ad = rl * 268 + wn + j * 16 + l16;
                        float v = acc[i][j][rr] + bvl[j];
                        if (RES) v += sRes[ad];
                        if (OUT == 1)
                            v = 0.5f * v *
                                (1.0f + erff(v * 0.70710678118654752f));
                        sRes[ad] = v;
                    }
                }
            }
        }
        __syncthreads();
        if (LN) {
            // row stats: wave wv handles rows wv*4 .. wv*4+3
#pragma unroll
            for (int r4 = 0; r4 < 4; r4++) {
                const int rl = wv * 4 + r4;
                const float4 vv = *(const float4*)(sRes + rl * 268 + lane * 4);
                float s = vv.x + vv.y + vv.z + vv.w;
                float ss = vv.x * vv.x + vv.y * vv.y + vv.z * vv.z + vv.w * vv.w;
                for (int m = 1; m < 64; m <<= 1) {
                    s += __shfl_xor(s, m);
                    ss += __shfl_xor(ss, m);
                }
                if (lane == 0) {
                    const float mean = s * (1.0f / 256.0f);
                    const float var = ss * (1.0f / 256.0f) - mean * mean;
                    sMean[rl] = mean;
                    sRstd[rl] = rsqrtf(fmaxf(var, 0.f) + 1e-5f);
                }
            }
        }
        // coalesced store of v
        {
            const float* sp = sRes + rowl * 268 + colb;
            if (OUT == 2) {
                float* op = outf + (size_t)gr * 256 + colb;
#pragma unroll
                for (int q = 0; q < 4; q++)
                    *(float4*)(op + q * 4) = *(const float4*)(sp + q * 4);
            } else {
                u16* op = outh + (size_t)gr * 256 + colb;
                *(uint4*)(op) = pack8(sp);
                *(uint4*)(op + 8) = pack8(sp + 8);
            }
        }
        if (LN) {
            __syncthreads();  // sMean/sRstd visibility
            const float m = sMean[rowl], rs = sRstd[rowl];
            const float* sp = sRes + rowl * 268 + colb;
            float h[16];
#pragma unroll
            for (int e = 0; e < 16; e++)
                h[e] = (sp[e] - m) * rs * sG[colb + e] + sBl[colb + e];
            u16* hp = hout + (size_t)gr * 256 + colb;
            *(uint4*)(hp) = pack8(h);
            *(uint4*)(hp + 8) = pack8(h + 8);
        }
    }
}

// ---------------------------------------------------------------------------
extern "C" void kernel_launch(void* const* d_in, const int* in_sizes, int n_in,
                              void* d_out, int out_size, void* d_ws,
                              size_t ws_size, hipStream_t stream) {
    const float* x = (const float*)d_in[0];
    const float* n1g = (const float*)d_in[1];
    const float* n1b = (const float*)d_in[2];
    const float* n2g = (const float*)d_in[3];
    const float* n2b = (const float*)d_in[4];
    const float* n3g = (const float*)d_in[5];
    const float* n3b = (const float*)d_in[6];
    const float* tWv = (const float*)d_in[7];
    const float* tbv = (const float*)d_in[8];
    const float* tWo = (const float*)d_in[9];
    const float* tbo = (const float*)d_in[10];
    const float* aWv = (const float*)d_in[11];
    const float* abv = (const float*)d_in[12];
    const float* aWo = (const float*)d_in[13];
    const float* abo = (const float*)d_in[14];
    const float* fW1 = (const float*)d_in[15];
    const float* fb1 = (const float*)d_in[16];
    const float* fW2 = (const float*)d_in[17];
    const float* fb2 = (const float*)d_in[18];
    float* outp = (float*)d_out;

    // Weight region (shared by both paths), then data slots.
    u16* wq = (u16*)d_ws;
    u16* tWoT = wq;                      //  65536  [256][256]
    u16* aWoT = wq + 65536;              //  65536
    u16* fW1T = wq + 131072;             // 131072  [512][256]
    u16* fW2T = wq + 262144;             // 131072  [256][512]
    u16* WcT1 = wq + 393216;             //  65536
    u16* WcT2 = wq + 458752;             //  65536
    u16* tWvB = wq + 524288;             //  65536
    u16* aWvB = wq + 589824;             //  65536
    float* bc1 = (float*)(wq + 655360);  //  256 fp32
    float* bc2 = (float*)(wq + 655872);  //  256 fp32
    const size_t W_ELEMS = 656384;
    const size_t SLOT = (size_t)NTOK * 256;
    u16* slot1 = wq + W_ELEMS;
    u16* slot2 = slot1 + SLOT;
    u16* slot3 = slot2 + SLOT;

    const size_t need_fast = (W_ELEMS + 3 * SLOT) * 2;  // ~97.3 MB

    // Fallback (round-4 proven) sizing.
    int t2c = 0;
    const int cands[4] = {256, 128, 64, 32};
    for (int ci = 0; ci < 4; ci++) {
        const size_t need = (W_ELEMS + SLOT + (size_t)NTOK * cands[ci]) * 2;
        if (need <= ws_size) { t2c = cands[ci]; break; }
    }
    if (ws_size < need_fast && t2c == 0) {
        k_diag<<<dim3(NTOK), 256, 0, stream>>>(outp, 512.0f + (float)(ws_size >> 20));
        return;
    }

    // --- per-launch weight prep (tiny, shared) ---
    k_transpose<<<dim3(16, 16, 6), 256, 0, stream>>>(
        tWo, aWo, fW1, fW2, tWv, aWv, tWoT, aWoT, fW1T, fW2T, tWvB, aWvB);
    k_gemm<3, u16><<<dim3(2, 2), 256, 0, stream>>>(
        tWoT, tWvB, nullptr, nullptr, WcT1, 256, 256, 256, 256);
    k_gemm<3, u16><<<dim3(2, 2), 256, 0, stream>>>(
        aWoT, aWvB, nullptr, nullptr, WcT2, 256, 256, 256, 256);
    k_bias_compose<<<dim3(2), 256, 0, stream>>>(tbv, tWo, tbo, abv, aWo, abo,
                                                bc1, bc2);

    if (ws_size >= need_fast) {
        // ================= FAST PATH =================
        const dim3 wgrid(TT / 64, BB);
        const dim3 fgrid(NTOK / 128);

        // K1: LN1 + temporal window -> a1 (slot1)
        k_ln_temporal<<<wgrid, 256, 0, stream>>>(x, n1g, n1b, slot1);

        // G1: r1 = x + a1@Wc1 + bc1 -> d_out (fp32); h2 = LN2(r1) -> slot2
        k_fused<0, 1, 2, 1><<<fgrid, 512, 0, stream>>>(
            slot1, slot1, 256, WcT1, 256, bc1, x, outp, nullptr, n2g, n2b,
            slot2);

        // G2: r2 = r1 + nbr(h2)@Wc2 + bc2 -> d_out in-place; h3 = LN3 -> slot3
        k_fused<1, 1, 2, 1><<<fgrid, 512, 0, stream>>>(
            slot2, slot2, 256, WcT2, 256, bc2, outp, outp, nullptr, n3g, n3b,
            slot3);

        // G3a/b: t2 = gelu(h3@W1 + b1), two 256-col halves -> slot1, slot2
        k_fused<0, 0, 1, 0><<<fgrid, 512, 0, stream>>>(
            slot3, slot3, 256, fW1T, 256, fb1, nullptr, nullptr, slot1,
            nullptr, nullptr, nullptr);
        k_fused<0, 0, 1, 0><<<fgrid, 512, 0, stream>>>(
            slot3, slot3, 256, fW1T + 256 * 256, 256, fb1 + 256, nullptr,
            nullptr, slot2, nullptr, nullptr, nullptr);

        // G4: out = r2 + t2@W2 + b2 -> d_out in-place (K=512)
        k_fused<0, 1, 2, 0><<<fgrid, 512, 0, stream>>>(
            slot1, slot2, 512, fW2T, 512, fb2, outp, outp, nullptr, nullptr,
            nullptr, nullptr);
        return;
    }

    // ================= FALLBACK (round-4 proven) =================
    u16* t1 = slot1;
    u16* t2 = slot2;
    const dim3 wgrid(TT / 64, BB);

    k_ln_temporal<<<wgrid, 256, 0, stream>>>(x, n1g, n1b, t1);
    k_gemm<2, float><<<dim3(2, 512), 256, 0, stream>>>(
        t1, WcT1, bc1, x, outp, NTOK, 256, 256, 256);

    k_ln_neighbor<<<wgrid, 256, 0, stream>>>(outp, n2g, n2b, t1);
    k_gemm<2, float><<<dim3(2, 512), 256, 0, stream>>>(
        t1, WcT2, bc2, outp, outp, NTOK, 256, 256, 256);

    k_ln<<<dim3(NTOK / 4), 256, 0, stream>>>(outp, n3g, n3b, t1);
    const int gx1 = (t2c + 127) / 128;
    for (int c0 = 0; c0 < 512; c0 += t2c) {
        k_gemm<1, u16><<<dim3(gx1, 512), 256, 0, stream>>>(
            t1, fW1T + (size_t)c0 * 256, fb1 + c0, nullptr, t2, NTOK, 256,
            t2c, 256);
        if (c0 == 0)
            k_gemm<2, float><<<dim3(2, 512), 256, 0, stream>>>(
                t2, fW2T + c0, fb2, outp, outp, NTOK, t2c, 256, 512);
        else
            k_gemm<4, float><<<dim3(2, 512), 256, 0, stream>>>(
                t2, fW2T + c0, nullptr, outp, outp, NTOK, t2c, 256, 512);
    }
}

// Round 6
// 486.680 us; speedup vs baseline: 1.3873x; 1.3873x over previous
//
#include <hip/hip_runtime.h>
#include <cstdint>
#include <cstddef>

// Problem constants (B=8, T=8192, D=256, H=16, K=3, decay=0.9, eps=1e-5)
// I/O dtype: fp32. Internal staging: bf16 (MFMA). ws >= 97.3 MB (confirmed r5).
#define TT 8192
#define BB 8
#define DD 256
#define NTOK (BB * TT)

typedef unsigned short u16;
typedef unsigned int u32;

typedef __attribute__((ext_vector_type(8))) short bf16x8;
typedef __attribute__((ext_vector_type(4))) float f32x4;

__device__ __forceinline__ float bf2f(u16 u) {
    u32 v = ((u32)u) << 16;
    float f;
    __builtin_memcpy(&f, &v, 4);
    return f;
}

__device__ __forceinline__ u16 f2bf(float f) {
    u32 v;
    __builtin_memcpy(&v, &f, 4);
    u32 r = (v + 0x7FFFu + ((v >> 16) & 1u)) >> 16;  // RNE
    return (u16)r;
}

__device__ __forceinline__ uint2 pack4(const float* v) {
    uint2 p;
    p.x = (u32)f2bf(v[0]) | ((u32)f2bf(v[1]) << 16);
    p.y = (u32)f2bf(v[2]) | ((u32)f2bf(v[3]) << 16);
    return p;
}

__device__ __forceinline__ void unpack4(uint2 p, float* v) {
    v[0] = bf2f((u16)(p.x & 0xFFFFu));
    v[1] = bf2f((u16)(p.x >> 16));
    v[2] = bf2f((u16)(p.y & 0xFFFFu));
    v[3] = bf2f((u16)(p.y >> 16));
}

__device__ __forceinline__ uint4 pack8(const float* v) {
    uint4 p;
    p.x = (u32)f2bf(v[0]) | ((u32)f2bf(v[1]) << 16);
    p.y = (u32)f2bf(v[2]) | ((u32)f2bf(v[3]) << 16);
    p.z = (u32)f2bf(v[4]) | ((u32)f2bf(v[5]) << 16);
    p.w = (u32)f2bf(v[6]) | ((u32)f2bf(v[7]) << 16);
    return p;
}

__device__ __forceinline__ void unpack8(uint4 p, float* v) {
    v[0] = bf2f((u16)(p.x & 0xFFFFu));
    v[1] = bf2f((u16)(p.x >> 16));
    v[2] = bf2f((u16)(p.y & 0xFFFFu));
    v[3] = bf2f((u16)(p.y >> 16));
    v[4] = bf2f((u16)(p.z & 0xFFFFu));
    v[5] = bf2f((u16)(p.z >> 16));
    v[6] = bf2f((u16)(p.w & 0xFFFFu));
    v[7] = bf2f((u16)(p.w >> 16));
}

// ---------------------------------------------------------------------------
__global__ __launch_bounds__(256) void k_diag(float* out, float code) {
    out[(size_t)blockIdx.x * 256 + threadIdx.x] = code;
}

// ---------------------------------------------------------------------------
// Weight transpose/convert fp32 -> bf16 (proven).
// ---------------------------------------------------------------------------
__global__ __launch_bounds__(256) void k_transpose(
    const float* s0, const float* s1, const float* s2, const float* s3,
    const float* s4, const float* s5,
    u16* d0, u16* d1, u16* d2, u16* d3, u16* d4, u16* d5) {
    const int z = blockIdx.z;
    const float* src;
    u16* dst;
    int K, N, tr;
    switch (z) {
        case 0: src = s0; dst = d0; K = 256; N = 256; tr = 1; break;
        case 1: src = s1; dst = d1; K = 256; N = 256; tr = 1; break;
        case 2: src = s2; dst = d2; K = 256; N = 512; tr = 1; break;
        case 3: src = s3; dst = d3; K = 512; N = 256; tr = 1; break;
        case 4: src = s4; dst = d4; K = 256; N = 256; tr = 0; break;
        default: src = s5; dst = d5; K = 256; N = 256; tr = 0; break;
    }
    const int nb = blockIdx.x * 32, kb = blockIdx.y * 32;
    if (nb >= N || kb >= K) return;
    const int tx = threadIdx.x & 31, ty = threadIdx.x >> 5;
    if (!tr) {
        for (int i = ty; i < 32; i += 8)
            dst[(size_t)(kb + i) * N + nb + tx] =
                f2bf(src[(size_t)(kb + i) * N + nb + tx]);
        return;
    }
    __shared__ u16 tile[32][33];
    for (int i = ty; i < 32; i += 8)
        tile[i][tx] = f2bf(src[(size_t)(kb + i) * N + nb + tx]);
    __syncthreads();
    for (int i = ty; i < 32; i += 8)
        dst[(size_t)(nb + i) * K + kb + tx] = tile[tx][i];
}

// ---------------------------------------------------------------------------
// Composed bias (fp32): bc[n] = sum_j bv[j]*Wo[j][n] + bo[n].  (proven)
// ---------------------------------------------------------------------------
__global__ __launch_bounds__(256) void k_bias_compose(
    const float* tbv, const float* tWo, const float* tbo,
    const float* abv, const float* aWo, const float* abo,
    float* bc1, float* bc2) {
    const float* bv = blockIdx.x ? abv : tbv;
    const float* Wo = blockIdx.x ? aWo : tWo;
    const float* bo = blockIdx.x ? abo : tbo;
    float* bc = blockIdx.x ? bc2 : bc1;
    const int n = threadIdx.x;
    float s = bo[n];
    for (int j = 0; j < 256; j++) s += bv[j] * Wo[j * 256 + n];
    bc[n] = s;
}

// ---------------------------------------------------------------------------
// LN1 + temporal decay window (H=16, left zero-pad per batch). (proven)
// ---------------------------------------------------------------------------
__global__ __launch_bounds__(256) void k_ln_temporal(
    const float* __restrict__ x, const float* __restrict__ gw,
    const float* __restrict__ bw, u16* __restrict__ out) {
    const int b = blockIdx.y;
    const int t0 = blockIdx.x * 64;
    const int tid = threadIdx.x;
    const int wv = tid >> 6, lane = tid & 63;
    const int d4 = lane * 4;
    __shared__ u16 hl[79 * 256];

    const float4 gv = *(const float4*)(gw + d4);
    const float4 bv = *(const float4*)(bw + d4);

    for (int i = wv; i < 79; i += 4) {
        const int t = t0 + i - 15;
        if (t < 0) {
            *(uint2*)(hl + i * 256 + d4) = make_uint2(0u, 0u);
            continue;
        }
        const float4 v = *(const float4*)(x + ((size_t)b * TT + t) * DD + d4);
        float s = v.x + v.y + v.z + v.w;
        float ss = v.x * v.x + v.y * v.y + v.z * v.z + v.w * v.w;
        for (int m = 1; m < 64; m <<= 1) {
            s += __shfl_xor(s, m);
            ss += __shfl_xor(ss, m);
        }
        const float mean = s * (1.0f / 256.0f);
        const float var = ss * (1.0f / 256.0f) - mean * mean;
        const float rs = rsqrtf(fmaxf(var, 0.f) + 1e-5f);
        float h[4] = {(v.x - mean) * rs * gv.x + bv.x,
                      (v.y - mean) * rs * gv.y + bv.y,
                      (v.z - mean) * rs * gv.z + bv.z,
                      (v.w - mean) * rs * gv.w + bv.w};
        *(uint2*)(hl + i * 256 + d4) = pack4(h);
    }
    __syncthreads();

    float tw[16];
    {
        float p = 1.f, s = 0.f;
        for (int j = 0; j < 16; j++) {
            tw[j] = p;
            s += p;
            p *= 0.9f;
        }
        const float inv = 1.f / s;
        for (int j = 0; j < 16; j++) tw[j] *= inv;
    }
    const int dc = (tid & 63) * 4;
    const int tg = (tid >> 6) * 16;
    for (int ot = tg; ot < tg + 16; ++ot) {
        float a[4] = {0.f, 0.f, 0.f, 0.f};
        for (int j = 0; j < 16; j++) {
            float h[4];
            unpack4(*(const uint2*)(hl + (ot + j) * 256 + dc), h);
            a[0] += tw[j] * h[0];
            a[1] += tw[j] * h[1];
            a[2] += tw[j] * h[2];
            a[3] += tw[j] * h[3];
        }
        *(uint2*)(out + ((size_t)b * TT + t0 + ot) * DD + dc) = pack4(a);
    }
}

// ---------------------------------------------------------------------------
// Prep-only MFMA GEMM (weight composition, 256x256). Proven (round 4).
// ---------------------------------------------------------------------------
__global__ __launch_bounds__(256) void k_gemm_prep(
    const u16* __restrict__ A, const u16* __restrict__ Wt,
    u16* out, int M, int K, int Nc, int ldw) {
    const int m0 = blockIdx.y * 128;
    const int n0 = blockIdx.x * 128;
    const int tid = threadIdx.x;
    const int wv = tid >> 6, lane = tid & 63;
    const int quad = lane >> 4, l16 = lane & 15;
    const int wm = (wv >> 1) * 64, wn = (wv & 1) * 64;

    __shared__ u16 lA[128 * 40];
    __shared__ u16 lB[128 * 40];

    f32x4 acc[4][4];
#pragma unroll
    for (int i = 0; i < 4; i++)
#pragma unroll
        for (int j = 0; j < 4; j++) acc[i][j] = (f32x4){0.f, 0.f, 0.f, 0.f};

    const int r = tid >> 2;
    const int c = tid & 3;

    for (int k0 = 0; k0 < K; k0 += 32) {
        __syncthreads();
        {
            const uint4 a0 = *(const uint4*)(A + (size_t)(m0 + r) * K + k0 + c * 8);
            const uint4 a1 = *(const uint4*)(A + (size_t)(m0 + r + 64) * K + k0 + c * 8);
            const uint4 b0 = *(const uint4*)(Wt + (size_t)(n0 + r) * ldw + k0 + c * 8);
            const uint4 b1 = *(const uint4*)(Wt + (size_t)(n0 + r + 64) * ldw + k0 + c * 8);
            *(uint4*)(lA + r * 40 + c * 8) = a0;
            *(uint4*)(lA + (r + 64) * 40 + c * 8) = a1;
            *(uint4*)(lB + r * 40 + c * 8) = b0;
            *(uint4*)(lB + (r + 64) * 40 + c * 8) = b1;
        }
        __syncthreads();
        bf16x8 af[4], bfr[4];
#pragma unroll
        for (int i = 0; i < 4; i++)
            af[i] = *(const bf16x8*)(lA + (wm + i * 16 + l16) * 40 + quad * 8);
#pragma unroll
        for (int j = 0; j < 4; j++)
            bfr[j] = *(const bf16x8*)(lB + (wn + j * 16 + l16) * 40 + quad * 8);
#pragma unroll
        for (int i = 0; i < 4; i++)
#pragma unroll
            for (int j = 0; j < 4; j++)
                acc[i][j] = __builtin_amdgcn_mfma_f32_16x16x32_bf16(
                    af[i], bfr[j], acc[i][j], 0, 0, 0);
    }

#pragma unroll
    for (int i = 0; i < 4; i++) {
        const int rowb = m0 + wm + i * 16 + quad * 4;
#pragma unroll
        for (int j = 0; j < 4; j++) {
            const int col = n0 + wn + j * 16 + l16;
#pragma unroll
            for (int rr = 0; rr < 4; rr++)
                out[(size_t)(rowb + rr) * Nc + col] = f2bf(acc[i][j][rr]);
        }
    }
}

// ---------------------------------------------------------------------------
// Main fused GEMM, 256 threads, tile 64(M) x 256(N): 4 waves, each 64x64
// (wn = wv*64), acc 4x4 f32x4 (round-4-proven register budget).
//   AMODE: 1 = 3-tap neighbor mean (edge-replicate per T=8192 batch) applied
//          to A rows during staging.
//   RES:   1 = fp32 residual added (res may alias outf elementwise).
//   GELU:  1 = exact GELU on (acc+bias), bf16 store to outh. (SF32=0 path)
//   SF32:  1 = fp32 store of (acc+bias[+res]) to outf.
//   LNOUT: 1 = also emit LayerNorm(row)*g+b as bf16 to hout.
// K = 256 or 512 (A2 supplies cols 256.. as a second [M][256] matrix).
// Epilogue runs in 4 chunks of 16 rows through LDS; all global I/O coalesced.
// ---------------------------------------------------------------------------
template <int AMODE, int RES, int GELU, int SF32, int LNOUT>
__global__ __launch_bounds__(256) void k_mega(
    const u16* __restrict__ A, const u16* __restrict__ A2, int K,
    const u16* __restrict__ Wt, int ldw, const float* __restrict__ bias,
    const float* res, float* outf, u16* __restrict__ outh,
    const float* __restrict__ lng, const float* __restrict__ lnb,
    u16* __restrict__ hout) {
    const int m0 = blockIdx.x * 64;
    const int t = threadIdx.x;
    const int lane = t & 63, wv = t >> 6;
    const int quad = lane >> 4, l16 = lane & 15;
    const int wn = wv * 64;

    __shared__ u16 sA[66 * 40];
    __shared__ u16 sA2[AMODE ? 64 * 40 : 8];
    __shared__ float sBuf[5120];  // K-loop: B tile (256x40 u16). Epi: 16x268 f32.
    u16* sB = (u16*)sBuf;
    float* sE = sBuf;
    __shared__ float sMean[16], sRstd[16];
    __shared__ float sG[LNOUT ? 256 : 1], sBl[LNOUT ? 256 : 1];

    if (LNOUT) {
        sG[t] = lng[t];
        sBl[t] = lnb[t];
    }

    f32x4 acc[4][4];
#pragma unroll
    for (int i = 0; i < 4; i++)
#pragma unroll
        for (int j = 0; j < 4; j++) acc[i][j] = (f32x4){0.f, 0.f, 0.f, 0.f};

    int rowLo = 0, rowHi = 0;
    if (AMODE) {
        rowLo = (m0 % TT == 0) ? m0 : m0 - 1;
        rowHi = ((m0 + 64) % TT == 0) ? (m0 + 63) : (m0 + 64);
    }

    const int ar = t >> 2, ac8 = (t & 3) * 8;  // A: 64 rows x 4 chunks
    for (int k0 = 0; k0 < K; k0 += 32) {
        const u16* Asrc = (k0 >= 256) ? A2 : A;
        const int kk = k0 & 255;
        __syncthreads();
        // stage A (bf16 rows, 64B per row-chunk)
        if (AMODE == 0) {
            *(uint4*)(sA + ar * 40 + ac8) =
                *(const uint4*)(Asrc + (size_t)(m0 + ar) * 256 + kk + ac8);
        } else {
            *(uint4*)(sA + (ar + 1) * 40 + ac8) =
                *(const uint4*)(Asrc + (size_t)(m0 + ar) * 256 + kk + ac8);
            if (t < 8) {
                const int hr = (t >> 2) ? rowHi : rowLo;
                const int dr = (t >> 2) ? 65 : 0;
                *(uint4*)(sA + dr * 40 + (t & 3) * 8) =
                    *(const uint4*)(Asrc + (size_t)hr * 256 + kk + (t & 3) * 8);
            }
        }
        // stage B: 256 N-rows x 32 k = 1024 chunks, 4 per thread
#pragma unroll
        for (int q = 0; q < 4; q++) {
            const int ch = t + q * 256;
            *(uint4*)(sB + (ch >> 2) * 40 + (ch & 3) * 8) =
                *(const uint4*)(Wt + (size_t)(ch >> 2) * ldw + k0 + (ch & 3) * 8);
        }
        __syncthreads();
        if (AMODE) {  // sA2[r] = mean(sA[r..r+2])  (proven in round 5)
            float v0[8], v1[8], v2[8], o[8];
            unpack8(*(const uint4*)(sA + ar * 40 + ac8), v0);
            unpack8(*(const uint4*)(sA + (ar + 1) * 40 + ac8), v1);
            unpack8(*(const uint4*)(sA + (ar + 2) * 40 + ac8), v2);
#pragma unroll
            for (int e = 0; e < 8; e++)
                o[e] = (v0[e] + v1[e] + v2[e]) * (1.0f / 3.0f);
            *(uint4*)(sA2 + ar * 40 + ac8) = pack8(o);
            __syncthreads();
        }
        const u16* Af = AMODE ? sA2 : sA;
        bf16x8 af[4], bfr[4];
#pragma unroll
        for (int i = 0; i < 4; i++)
            af[i] = *(const bf16x8*)(Af + (i * 16 + l16) * 40 + quad * 8);
#pragma unroll
        for (int j = 0; j < 4; j++)
            bfr[j] = *(const bf16x8*)(sB + (wn + j * 16 + l16) * 40 + quad * 8);
#pragma unroll
        for (int i = 0; i < 4; i++)
#pragma unroll
            for (int j = 0; j < 4; j++)
                acc[i][j] = __builtin_amdgcn_mfma_f32_16x16x32_bf16(
                    af[i], bfr[j], acc[i][j], 0, 0, 0);
    }

    float bvl[4];
#pragma unroll
    for (int j = 0; j < 4; j++) bvl[j] = bias[wn + j * 16 + l16];

    // Epilogue: 4 chunks of 16 rows. Chunk cch uses acc[cch][*].
    const int row = t >> 4;          // 0..15
    const int colb = (t & 15) * 16;  // 0..240
    for (int cch = 0; cch < 4; cch++) {
        const int gr = m0 + cch * 16 + row;
        __syncthreads();  // guard sE/sB reuse + prior chunk reads
        if (RES) {
            const float* rp = res + (size_t)gr * 256 + colb;
            float* sp = sE + row * 268 + colb;
#pragma unroll
            for (int q = 0; q < 4; q++)
                *(float4*)(sp + q * 4) = *(const float4*)(rp + q * 4);
        }
        __syncthreads();
        // each wave adds its columns for these 16 rows (i == cch)
        {
#pragma unroll
            for (int j = 0; j < 4; j++) {
#pragma unroll
                for (int rr = 0; rr < 4; rr++) {
                    const int rl = quad * 4 + rr;
                    const int ad = rl * 268 + wn + j * 16 + l16;
                    float v = acc[cch][j][rr] + bvl[j];
                    if (RES) v += sE[ad];
                    if (GELU)
                        v = 0.5f * v * (1.0f + erff(v * 0.70710678118654752f));
                    sE[ad] = v;
                }
            }
        }
        __syncthreads();
        if (LNOUT) {  // row stats: wave wv -> rows wv*4..wv*4+3
#pragma unroll
            for (int r4 = 0; r4 < 4; r4++) {
                const int rl = wv * 4 + r4;
                const float4 vv = *(const float4*)(sE + rl * 268 + lane * 4);
                float s = vv.x + vv.y + vv.z + vv.w;
                float ss = vv.x * vv.x + vv.y * vv.y + vv.z * vv.z + vv.w * vv.w;
                for (int m = 1; m < 64; m <<= 1) {
                    s += __shfl_xor(s, m);
                    ss += __shfl_xor(ss, m);
                }
                if (lane == 0) {
                    const float mean = s * (1.0f / 256.0f);
                    const float var = ss * (1.0f / 256.0f) - mean * mean;
                    sMean[rl] = mean;
                    sRstd[rl] = rsqrtf(fmaxf(var, 0.f) + 1e-5f);
                }
            }
            __syncthreads();
        }
        const float* sp = sE + row * 268 + colb;
        if (SF32) {
            float* op = outf + (size_t)gr * 256 + colb;
#pragma unroll
            for (int q = 0; q < 4; q++)
                *(float4*)(op + q * 4) = *(const float4*)(sp + q * 4);
        }
        if (GELU) {
            u16* op = outh + (size_t)gr * 256 + colb;
            *(uint4*)op = pack8(sp);
            *(uint4*)(op + 8) = pack8(sp + 8);
        }
        if (LNOUT) {
            const float m = sMean[row], rs = sRstd[row];
            float h[16];
#pragma unroll
            for (int e = 0; e < 16; e++)
                h[e] = (sp[e] - m) * rs * sG[colb + e] + sBl[colb + e];
            u16* hp = hout + (size_t)gr * 256 + colb;
            *(uint4*)hp = pack8(h);
            *(uint4*)(hp + 8) = pack8(h + 8);
        }
    }
}

// ---------------------------------------------------------------------------
extern "C" void kernel_launch(void* const* d_in, const int* in_sizes, int n_in,
                              void* d_out, int out_size, void* d_ws,
                              size_t ws_size, hipStream_t stream) {
    const float* x = (const float*)d_in[0];
    const float* n1g = (const float*)d_in[1];
    const float* n1b = (const float*)d_in[2];
    const float* n2g = (const float*)d_in[3];
    const float* n2b = (const float*)d_in[4];
    const float* n3g = (const float*)d_in[5];
    const float* n3b = (const float*)d_in[6];
    const float* tWv = (const float*)d_in[7];
    const float* tbv = (const float*)d_in[8];
    const float* tWo = (const float*)d_in[9];
    const float* tbo = (const float*)d_in[10];
    const float* aWv = (const float*)d_in[11];
    const float* abv = (const float*)d_in[12];
    const float* aWo = (const float*)d_in[13];
    const float* abo = (const float*)d_in[14];
    const float* fW1 = (const float*)d_in[15];
    const float* fb1 = (const float*)d_in[16];
    const float* fW2 = (const float*)d_in[17];
    const float* fb2 = (const float*)d_in[18];
    float* outp = (float*)d_out;

    u16* wq = (u16*)d_ws;
    u16* tWoT = wq;                      //  65536  [256][256]
    u16* aWoT = wq + 65536;              //  65536
    u16* fW1T = wq + 131072;             // 131072  [512][256]
    u16* fW2T = wq + 262144;             // 131072  [256][512]
    u16* WcT1 = wq + 393216;             //  65536
    u16* WcT2 = wq + 458752;             //  65536
    u16* tWvB = wq + 524288;             //  65536
    u16* aWvB = wq + 589824;             //  65536
    float* bc1 = (float*)(wq + 655360);  //  256 fp32
    float* bc2 = (float*)(wq + 655872);  //  256 fp32
    const size_t W_ELEMS = 656384;
    const size_t SLOT = (size_t)NTOK * 256;
    u16* slot1 = wq + W_ELEMS;
    u16* slot2 = slot1 + SLOT;
    u16* slot3 = slot2 + SLOT;

    const size_t need = (W_ELEMS + 3 * SLOT) * 2;  // ~97.3 MB (fits: r5)
    if (ws_size < need) {
        k_diag<<<dim3(NTOK), 256, 0, stream>>>(outp,
                                               512.0f + (float)(ws_size >> 20));
        return;
    }

    // --- weight prep (tiny) ---
    k_transpose<<<dim3(16, 16, 6), 256, 0, stream>>>(
        tWo, aWo, fW1, fW2, tWv, aWv, tWoT, aWoT, fW1T, fW2T, tWvB, aWvB);
    k_gemm_prep<<<dim3(2, 2), 256, 0, stream>>>(tWoT, tWvB, WcT1, 256, 256,
                                                256, 256);
    k_gemm_prep<<<dim3(2, 2), 256, 0, stream>>>(aWoT, aWvB, WcT2, 256, 256,
                                                256, 256);
    k_bias_compose<<<dim3(2), 256, 0, stream>>>(tbv, tWo, tbo, abv, aWo, abo,
                                                bc1, bc2);

    const dim3 mg(NTOK / 64);

    // P1: agg1 = temporal(LN1(x)) -> slot1 (bf16)
    k_ln_temporal<<<dim3(TT / 64, BB), 256, 0, stream>>>(x, n1g, n1b, slot1);

    // P2: r1 = x + agg1@Wc1 + bc1 -> d_out (fp32); h2 = LN2(r1) -> slot2
    k_mega<0, 1, 0, 1, 1><<<mg, 256, 0, stream>>>(
        slot1, slot1, 256, WcT1, 256, bc1, x, outp, nullptr, n2g, n2b, slot2);

    // P3: r2 = r1 + nbr(h2)@Wc2 + bc2 -> d_out (in-place); h3 = LN3 -> slot1
    k_mega<1, 1, 0, 1, 1><<<mg, 256, 0, stream>>>(
        slot2, slot2, 256, WcT2, 256, bc2, outp, outp, nullptr, n3g, n3b,
        slot1);

    // P4/P5: t2 = gelu(h3@W1 + b1) halves -> slot2, slot3 (bf16)
    k_mega<0, 0, 1, 0, 0><<<mg, 256, 0, stream>>>(
        slot1, slot1, 256, fW1T, 256, fb1, nullptr, nullptr, slot2, nullptr,
        nullptr, nullptr);
    k_mega<0, 0, 1, 0, 0><<<mg, 256, 0, stream>>>(
        slot1, slot1, 256, fW1T + 256 * 256, 256, fb1 + 256, nullptr, nullptr,
        slot3, nullptr, nullptr, nullptr);

    // P6: out = r2 + [t2a,t2b]@W2 + b2 -> d_out (in-place, K=512)
    k_mega<0, 1, 0, 1, 0><<<mg, 256, 0, stream>>>(
        slot2, slot3, 512, fW2T, 512, fb2, outp, outp, nullptr, nullptr,
        nullptr, nullptr);
}